// Round 11
// baseline (233.978 us; speedup 1.0000x reference)
//
#include <hip/hip_runtime.h>
#include <hip/hip_bf16.h>
#include <math.h>

typedef __attribute__((ext_vector_type(4))) float f32x4;
typedef __attribute__((ext_vector_type(4))) int   i32x4;
typedef __attribute__((ext_vector_type(8))) short short8;

#define NN 8192
#define LOG2E 1.44269504088896f

// f32 -> bf16 bits, round-to-nearest-even
__device__ __forceinline__ unsigned f2bfu(float x) {
    unsigned u = __float_as_uint(x);
    u += 0x7FFFu + ((u >> 16) & 1u);
    return u >> 16;
}
__device__ __forceinline__ float expneg(float s) {   // exp(-s)
    return __builtin_amdgcn_exp2f(-LOG2E * s);
}

// ---------------------------------------------------------------------------
// P1: h = x @ W1  [8192,500]@[500,64] with W1 staged in LDS. 512 blocks x
// 16 rows (4 rows/wave). Writes fsrc/edst = exp(-h.a halves).
// ---------------------------------------------------------------------------
#define P1_CHUNK 100
__global__ __launch_bounds__(256) void p1_kernel(
    const float* __restrict__ x, const float* __restrict__ W1,
    const float* __restrict__ a1, float* __restrict__ h,
    float* __restrict__ fsrc, float* __restrict__ edst)
{
    __shared__ float wtile[P1_CHUNK * 64];
    const int lane = threadIdx.x & 63;
    const int w    = threadIdx.x >> 6;
    const int r0   = blockIdx.x * 16 + w * 4;

    float acc[4];
#pragma unroll
    for (int r = 0; r < 4; ++r) acc[r] = 0.f;

    for (int c = 0; c < 5; ++c) {
        const int kb = c * P1_CHUNK;
        __syncthreads();
        for (int idx = threadIdx.x; idx < P1_CHUNK * 64; idx += 256)
            wtile[idx] = W1[kb * 64 + idx];
        __syncthreads();
        for (int kk = 0; kk < P1_CHUNK; kk += 4) {
            float w0 = wtile[(kk + 0) * 64 + lane];
            float w1 = wtile[(kk + 1) * 64 + lane];
            float w2 = wtile[(kk + 2) * 64 + lane];
            float w3 = wtile[(kk + 3) * 64 + lane];
#pragma unroll
            for (int r = 0; r < 4; ++r) {
                f32x4 xv = *(const f32x4*)(x + (size_t)(r0 + r) * 500 + kb + kk);
                acc[r] = fmaf(xv[0], w0, acc[r]);
                acc[r] = fmaf(xv[1], w1, acc[r]);
                acc[r] = fmaf(xv[2], w2, acc[r]);
                acc[r] = fmaf(xv[3], w3, acc[r]);
            }
        }
    }
    float a_s = a1[lane], a_d = a1[64 + lane];
#pragma unroll
    for (int r = 0; r < 4; ++r) {
        h[(size_t)(r0 + r) * 64 + lane] = acc[r];
        float ps = acc[r] * a_s, pd = acc[r] * a_d;
        for (int off = 32; off > 0; off >>= 1) {
            ps += __shfl_down(ps, off); pd += __shfl_down(pd, off);
        }
        if (lane == 0) {
            fsrc[r0 + r] = expneg(ps);
            edst[r0 + r] = expneg(pd);
        }
    }
}

// ---------------------------------------------------------------------------
// Swizzle f32 matrix into bf16 B-fragment order:
// hB[kb][nb][lane][i] = bf16( h[kb*32 + (lane>>4)*8 + i][nb*16 + (lane&15)] )
// ---------------------------------------------------------------------------
__global__ __launch_bounds__(256) void swizzle_kernel(
    const float* __restrict__ h, short* __restrict__ hB,
    int nblk, int ncols, int total)
{
    int tid = blockIdx.x * 256 + threadIdx.x;
    if (tid >= total) return;
    int i  = tid & 7;
    int l  = (tid >> 3) & 63;
    int t2 = tid >> 9;
    int nb = t2 % nblk;
    int kb = t2 / nblk;
    int row = kb * 32 + (l >> 4) * 8 + i;
    int col = nb * 16 + (l & 15);
    float v = h[(size_t)row * ncols + col];
    hB[tid] = (short)f2bfu(v);
}

// ---------------------------------------------------------------------------
// FUSED GAT layer 1. Block = 8 waves x 512 thr, __launch_bounds__(512,4)
// forces VGPR<=128 -> 16 waves/CU. Wave owns mb (16 rows) x seg (16 kb).
// B-slice (64KB) + Es (edst slice, 2KB) staged in LDS once.
// K-loop: 2 clean f32 adj line-loads + LDS e-reads + VALU sigmoid + bf16(adj)
// pack/store (load-layout, clean 64B lines) + shuffle-to-fragment + 4 MFMA.
// ---------------------------------------------------------------------------
__global__ __launch_bounds__(512, 4) void fused1_kernel(
    const float* __restrict__ adj, const float* __restrict__ fsrc,
    const float* __restrict__ edst, const short* __restrict__ Bfrag,
    short* __restrict__ adjBp, float* __restrict__ outp,
    float* __restrict__ normpart)
{
    __shared__ __align__(16) short Bs[16 * 4 * 64 * 8];  // 64KB
    __shared__ __align__(16) float Es[512];              // 2KB
    const int tid  = threadIdx.x;
    const int lane = tid & 63;
    const int w    = tid >> 6;
    const int seg  = blockIdx.y;
    const int mb   = blockIdx.x * 8 + w;

    {
        const short8* src = (const short8*)(Bfrag) + (size_t)seg * (16 * 4 * 64);
        short8* dst = (short8*)Bs;
#pragma unroll
        for (int j = 0; j < 8; ++j)
            dst[tid + 512 * j] = src[tid + 512 * j];
        Es[tid] = edst[seg * 512 + tid];
    }
    __syncthreads();

    const int r = lane >> 2;       // load-layout row 0..15
    const int q = lane & 3;        // load-layout col quarter

    const float F_i = fsrc[mb * 16 + r];
    const float* arow = adj + (size_t)(mb * 16 + r) * NN;
    short* abrow = adjBp + (size_t)(mb * 16 + r) * NN;

    const int fg = lane >> 4;
    const int fr = lane & 15;
    const int s0 = fr * 4 + (fg & 1) * 2;
    const int s1 = s0 + 1;
    const bool lowhalf = (fg < 2);

    f32x4 acc[4];
#pragma unroll
    for (int nb = 0; nb < 4; ++nb) acc[nb] = (f32x4){0.f, 0.f, 0.f, 0.f};
    float nacc = 0.f;

    for (int k = 0; k < 16; ++k) {
        const int col0 = (seg * 16 + k) * 32;
        f32x4 a0 = *(const f32x4*)(arow + col0 + q * 4);
        f32x4 a1 = *(const f32x4*)(arow + col0 + 16 + q * 4);
        f32x4 e0 = *(const f32x4*)&Es[k * 32 + q * 4];
        f32x4 e1 = *(const f32x4*)&Es[k * 32 + 16 + q * 4];

        // bf16 adj copy for layer 2 (load-layout chunks: 4 lanes = 64B line)
        i32x4 ab;
        ab[0] = (int)(f2bfu(a0[0]) | (f2bfu(a0[1]) << 16));
        ab[1] = (int)(f2bfu(a0[2]) | (f2bfu(a0[3]) << 16));
        ab[2] = (int)(f2bfu(a1[0]) | (f2bfu(a1[1]) << 16));
        ab[3] = (int)(f2bfu(a1[2]) | (f2bfu(a1[3]) << 16));
        *(i32x4*)(abrow + col0 + q * 8) = ab;

        float v[8];
#pragma unroll
        for (int t = 0; t < 4; ++t) {
            float sg  = __builtin_amdgcn_rcpf(fmaf(F_i, e0[t], 1.0f));
            float att = sg * a0[t];
            nacc = fmaf(att, att, nacc);
            v[t] = att;
        }
#pragma unroll
        for (int t = 0; t < 4; ++t) {
            float sg  = __builtin_amdgcn_rcpf(fmaf(F_i, e1[t], 1.0f));
            float att = sg * a1[t];
            nacc = fmaf(att, att, nacc);
            v[4 + t] = att;
        }
        int d0 = (int)(f2bfu(v[0]) | (f2bfu(v[1]) << 16));
        int d1 = (int)(f2bfu(v[2]) | (f2bfu(v[3]) << 16));
        int d2 = (int)(f2bfu(v[4]) | (f2bfu(v[5]) << 16));
        int d3 = (int)(f2bfu(v[6]) | (f2bfu(v[7]) << 16));

        int p00 = __shfl(d0, s0, 64), p01 = __shfl(d1, s0, 64);
        int p10 = __shfl(d0, s1, 64), p11 = __shfl(d1, s1, 64);
        int q00 = __shfl(d2, s0, 64), q01 = __shfl(d3, s0, 64);
        int q10 = __shfl(d2, s1, 64), q11 = __shfl(d3, s1, 64);
        i32x4 wv;
        wv[0] = lowhalf ? p00 : q00;
        wv[1] = lowhalf ? p01 : q01;
        wv[2] = lowhalf ? p10 : q10;
        wv[3] = lowhalf ? p11 : q11;
        short8 af = *(short8*)&wv;

#pragma unroll
        for (int nb = 0; nb < 4; ++nb) {
            short8 bf = *(const short8*)&Bs[((k * 4 + nb) * 64 + lane) * 8];
            acc[nb] = __builtin_amdgcn_mfma_f32_16x16x32_bf16(af, bf, acc[nb], 0, 0, 0);
        }
    }

    nacc += __shfl_xor(nacc, 1);
    nacc += __shfl_xor(nacc, 2);
    if (q == 0) normpart[(mb * 16 + r) * 16 + seg] = nacc;

#pragma unroll
    for (int nb = 0; nb < 4; ++nb)
#pragma unroll
        for (int rr = 0; rr < 4; ++rr)
            outp[((size_t)seg * NN + mb * 16 + fg * 4 + rr) * 64 + nb * 16 + fr]
                = acc[nb][rr];
}

// ---------------------------------------------------------------------------
// FUSED GAT layer 2: reads bf16 adjBp (L3-resident, half the bytes), NBLK=1.
// ---------------------------------------------------------------------------
__global__ __launch_bounds__(512, 4) void fused2_kernel(
    const short* __restrict__ adjBp, const float* __restrict__ fsrc,
    const float* __restrict__ edst, const short* __restrict__ Bfrag,
    float* __restrict__ outp, float* __restrict__ normpart)
{
    __shared__ __align__(16) short Bs[16 * 64 * 8];   // 16KB
    __shared__ __align__(16) float Es[512];
    const int tid  = threadIdx.x;
    const int lane = tid & 63;
    const int w    = tid >> 6;
    const int seg  = blockIdx.y;
    const int mb   = blockIdx.x * 8 + w;

    {
        const short8* src = (const short8*)(Bfrag) + (size_t)seg * (16 * 64);
        short8* dst = (short8*)Bs;
#pragma unroll
        for (int j = 0; j < 2; ++j)
            dst[tid + 512 * j] = src[tid + 512 * j];
        Es[tid] = edst[seg * 512 + tid];
    }
    __syncthreads();

    const int r = lane >> 2;
    const int q = lane & 3;

    const float F_i = fsrc[mb * 16 + r];
    const short* abrow = adjBp + (size_t)(mb * 16 + r) * NN;

    const int fg = lane >> 4;
    const int fr = lane & 15;
    const int s0 = fr * 4 + (fg & 1) * 2;
    const int s1 = s0 + 1;
    const bool lowhalf = (fg < 2);

    f32x4 acc = (f32x4){0.f, 0.f, 0.f, 0.f};
    float nacc = 0.f;

    for (int k = 0; k < 16; ++k) {
        const int col0 = (seg * 16 + k) * 32;
        i32x4 ab = *(const i32x4*)(abrow + col0 + q * 8);
        f32x4 e0 = *(const f32x4*)&Es[k * 32 + q * 4];
        f32x4 e1 = *(const f32x4*)&Es[k * 32 + 16 + q * 4];

        float a[8];
#pragma unroll
        for (int t = 0; t < 4; ++t) {
            a[2 * t]     = __uint_as_float(((unsigned)ab[t]) << 16);
            a[2 * t + 1] = __uint_as_float(((unsigned)ab[t]) & 0xFFFF0000u);
        }
        float v[8];
#pragma unroll
        for (int t = 0; t < 4; ++t) {
            float sg  = __builtin_amdgcn_rcpf(fmaf(F_i, e0[t], 1.0f));
            float att = sg * a[t];
            nacc = fmaf(att, att, nacc);
            v[t] = att;
        }
#pragma unroll
        for (int t = 0; t < 4; ++t) {
            float sg  = __builtin_amdgcn_rcpf(fmaf(F_i, e1[t], 1.0f));
            float att = sg * a[4 + t];
            nacc = fmaf(att, att, nacc);
            v[4 + t] = att;
        }
        int d0 = (int)(f2bfu(v[0]) | (f2bfu(v[1]) << 16));
        int d1 = (int)(f2bfu(v[2]) | (f2bfu(v[3]) << 16));
        int d2 = (int)(f2bfu(v[4]) | (f2bfu(v[5]) << 16));
        int d3 = (int)(f2bfu(v[6]) | (f2bfu(v[7]) << 16));

        int p00 = __shfl(d0, s0, 64), p01 = __shfl(d1, s0, 64);
        int p10 = __shfl(d0, s1, 64), p11 = __shfl(d1, s1, 64);
        int q00 = __shfl(d2, s0, 64), q01 = __shfl(d3, s0, 64);
        int q10 = __shfl(d2, s1, 64), q11 = __shfl(d3, s1, 64);
        i32x4 wv;
        wv[0] = lowhalf ? p00 : q00;
        wv[1] = lowhalf ? p01 : q01;
        wv[2] = lowhalf ? p10 : q10;
        wv[3] = lowhalf ? p11 : q11;
        short8 af = *(short8*)&wv;

        short8 bf = *(const short8*)&Bs[(k * 64 + lane) * 8];
        acc = __builtin_amdgcn_mfma_f32_16x16x32_bf16(af, bf, acc, 0, 0, 0);
    }

    nacc += __shfl_xor(nacc, 1);
    nacc += __shfl_xor(nacc, 2);
    if (q == 0) normpart[(mb * 16 + r) * 16 + seg] = nacc;

#pragma unroll
    for (int rr = 0; rr < 4; ++rr)
        outp[((size_t)seg * NN + mb * 16 + fg * 4 + rr) * 16 + fr] = acc[rr];
}

// ---------------------------------------------------------------------------
// R1: h1[i][f] = sum_seg outp1 / (sqrt(sum_p normpart1[i][p]) + 1e-10)
// ---------------------------------------------------------------------------
__global__ __launch_bounds__(256) void r1_kernel(
    const float* __restrict__ outp, const float* __restrict__ normpart,
    float* __restrict__ h1)
{
    int tid = blockIdx.x * 256 + threadIdx.x;
    int i = tid >> 6, f = tid & 63;
    float s = 0.f;
#pragma unroll
    for (int sg = 0; sg < 16; ++sg)
        s += outp[((size_t)sg * NN + i) * 64 + f];
    float n = 0.f;
#pragma unroll
    for (int p = 0; p < 16; ++p) n += normpart[i * 16 + p];
    h1[tid] = s / (sqrtf(n) + 1e-10f);
}

// ---------------------------------------------------------------------------
// P2: z = h1 @ W2 (padded to 16 cols), fsrc2/edst2 = exp(-z . a2 halves)
// ---------------------------------------------------------------------------
__global__ __launch_bounds__(256) void p2_kernel(
    const float* __restrict__ h1, const float* __restrict__ W2,
    const float* __restrict__ a2, float* __restrict__ z,
    float* __restrict__ fsrc2, float* __restrict__ edst2)
{
    int i = blockIdx.x * 256 + threadIdx.x;
    if (i >= NN) return;
    float zz[10];
#pragma unroll
    for (int c = 0; c < 10; ++c) zz[c] = 0.f;
    for (int f = 0; f < 64; ++f) {
        float hv = h1[(size_t)i * 64 + f];
#pragma unroll
        for (int c = 0; c < 10; ++c) zz[c] = fmaf(hv, W2[f * 10 + c], zz[c]);
    }
    float s1 = 0.f, s2 = 0.f;
#pragma unroll
    for (int c = 0; c < 10; ++c) {
        s1 = fmaf(zz[c], a2[c], s1);
        s2 = fmaf(zz[c], a2[10 + c], s2);
        z[(size_t)i * 16 + c] = zz[c];
    }
#pragma unroll
    for (int c = 10; c < 16; ++c) z[(size_t)i * 16 + c] = 0.f;
    fsrc2[i] = expneg(s1);
    edst2[i] = expneg(s2);
}

// ---------------------------------------------------------------------------
// R2: h2 = partials/norm, then log_softmax over 10 classes -> d_out
// ---------------------------------------------------------------------------
__global__ __launch_bounds__(256) void r2_kernel(
    const float* __restrict__ outp, const float* __restrict__ normpart,
    float* __restrict__ out)
{
    int i = blockIdx.x * 256 + threadIdx.x;
    if (i >= NN) return;
    float n = 0.f;
#pragma unroll
    for (int p = 0; p < 16; ++p) n += normpart[i * 16 + p];
    float inv = 1.0f / (sqrtf(n) + 1e-10f);
    float v[10];
    float m = -1e30f;
#pragma unroll
    for (int c = 0; c < 10; ++c) {
        float s = 0.f;
#pragma unroll
        for (int sg = 0; sg < 16; ++sg)
            s += outp[((size_t)sg * NN + i) * 16 + c];
        v[c] = s * inv;
        m = fmaxf(m, v[c]);
    }
    float es = 0.f;
#pragma unroll
    for (int c = 0; c < 10; ++c) es += expf(v[c] - m);
    float lse = m + logf(es);
#pragma unroll
    for (int c = 0; c < 10; ++c) out[(size_t)i * 10 + c] = v[c] - lse;
}

extern "C" void kernel_launch(void* const* d_in, const int* in_sizes, int n_in,
                              void* d_out, int out_size, void* d_ws, size_t ws_size,
                              hipStream_t stream)
{
    const float* x   = (const float*)d_in[0];
    const float* adj = (const float*)d_in[1];
    const float* W1  = (const float*)d_in[2];
    const float* a1  = (const float*)d_in[3];
    const float* W2  = (const float*)d_in[4];
    const float* a2  = (const float*)d_in[5];
    float* out = (float*)d_out;

    char* ws = (char*)d_ws;
    size_t off = 0;
    auto alloc = [&](size_t bytes) -> void* {
        void* p = ws + off;
        off += (bytes + 255) & ~(size_t)255;
        return p;
    };
    short* adjBp  = (short*)alloc((size_t)NN * NN * 2);          // 134MB
    float* h      = (float*)alloc((size_t)NN * 64 * 4);
    float* fsrc1  = (float*)alloc((size_t)NN * 4);
    float* edst1  = (float*)alloc((size_t)NN * 4);
    short* hB1    = (short*)alloc((size_t)NN * 64 * 2);
    float* outp1  = (float*)alloc((size_t)16 * NN * 64 * 4);     // 33.5MB
    float* normp1 = (float*)alloc((size_t)NN * 16 * 4);
    float* h1     = (float*)alloc((size_t)NN * 64 * 4);
    float* z      = (float*)alloc((size_t)NN * 16 * 4);
    float* fsrc2  = (float*)alloc((size_t)NN * 4);
    float* edst2  = (float*)alloc((size_t)NN * 4);
    short* zB     = (short*)alloc((size_t)NN * 16 * 2);
    float* outp2  = (float*)alloc((size_t)16 * NN * 16 * 4);     // 8.4MB
    float* normp2 = (float*)alloc((size_t)NN * 16 * 4);

    hipLaunchKernelGGL(p1_kernel, dim3(NN / 16), dim3(256), 0, stream,
                       x, W1, a1, h, fsrc1, edst1);
    hipLaunchKernelGGL(swizzle_kernel, dim3(2048), dim3(256), 0, stream,
                       h, hB1, 4, 64, NN * 64);
    hipLaunchKernelGGL(fused1_kernel, dim3(64, 16), dim3(512), 0, stream,
                       adj, fsrc1, edst1, hB1, adjBp, outp1, normp1);
    hipLaunchKernelGGL(r1_kernel, dim3(2048), dim3(256), 0, stream,
                       outp1, normp1, h1);
    hipLaunchKernelGGL(p2_kernel, dim3(32), dim3(256), 0, stream,
                       h1, W2, a2, z, fsrc2, edst2);
    hipLaunchKernelGGL(swizzle_kernel, dim3(512), dim3(256), 0, stream,
                       z, zB, 1, 16, NN * 16);
    hipLaunchKernelGGL(fused2_kernel, dim3(64, 16), dim3(512), 0, stream,
                       adjBp, fsrc2, edst2, zB, outp2, normp2);
    hipLaunchKernelGGL(r2_kernel, dim3(32), dim3(256), 0, stream,
                       outp2, normp2, out);
}

// Round 12
// 195.335 us; speedup vs baseline: 1.1978x; 1.1978x over previous
//
#include <hip/hip_runtime.h>
#include <hip/hip_bf16.h>
#include <math.h>

typedef __attribute__((ext_vector_type(4))) float f32x4;
typedef __attribute__((ext_vector_type(4))) int   i32x4;
typedef __attribute__((ext_vector_type(8))) short short8;

#define NN 8192
#define LOG2E 1.44269504088896f

// f32 -> bf16 bits, round-to-nearest-even
__device__ __forceinline__ unsigned f2bfu(float x) {
    unsigned u = __float_as_uint(x);
    u += 0x7FFFu + ((u >> 16) & 1u);
    return u >> 16;
}
__device__ __forceinline__ float expneg(float s) {   // exp(-s)
    return __builtin_amdgcn_exp2f(-LOG2E * s);
}

// ---------------------------------------------------------------------------
// P1: h = x @ W1  [8192,500]@[500,64] with W1 staged in LDS. 512 blocks x
// 16 rows (4 rows/wave). Writes fsrc/edst = exp(-h.a halves).
// ---------------------------------------------------------------------------
#define P1_CHUNK 100
__global__ __launch_bounds__(256) void p1_kernel(
    const float* __restrict__ x, const float* __restrict__ W1,
    const float* __restrict__ a1, float* __restrict__ h,
    float* __restrict__ fsrc, float* __restrict__ edst)
{
    __shared__ float wtile[P1_CHUNK * 64];
    const int lane = threadIdx.x & 63;
    const int w    = threadIdx.x >> 6;
    const int r0   = blockIdx.x * 16 + w * 4;

    float acc[4];
#pragma unroll
    for (int r = 0; r < 4; ++r) acc[r] = 0.f;

    for (int c = 0; c < 5; ++c) {
        const int kb = c * P1_CHUNK;
        __syncthreads();
        for (int idx = threadIdx.x; idx < P1_CHUNK * 64; idx += 256)
            wtile[idx] = W1[kb * 64 + idx];
        __syncthreads();
        for (int kk = 0; kk < P1_CHUNK; kk += 4) {
            float w0 = wtile[(kk + 0) * 64 + lane];
            float w1 = wtile[(kk + 1) * 64 + lane];
            float w2 = wtile[(kk + 2) * 64 + lane];
            float w3 = wtile[(kk + 3) * 64 + lane];
#pragma unroll
            for (int r = 0; r < 4; ++r) {
                f32x4 xv = *(const f32x4*)(x + (size_t)(r0 + r) * 500 + kb + kk);
                acc[r] = fmaf(xv[0], w0, acc[r]);
                acc[r] = fmaf(xv[1], w1, acc[r]);
                acc[r] = fmaf(xv[2], w2, acc[r]);
                acc[r] = fmaf(xv[3], w3, acc[r]);
            }
        }
    }
    float a_s = a1[lane], a_d = a1[64 + lane];
#pragma unroll
    for (int r = 0; r < 4; ++r) {
        h[(size_t)(r0 + r) * 64 + lane] = acc[r];
        float ps = acc[r] * a_s, pd = acc[r] * a_d;
        for (int off = 32; off > 0; off >>= 1) {
            ps += __shfl_down(ps, off); pd += __shfl_down(pd, off);
        }
        if (lane == 0) {
            fsrc[r0 + r] = expneg(ps);
            edst[r0 + r] = expneg(pd);
        }
    }
}

// ---------------------------------------------------------------------------
// Swizzle f32 matrix into bf16 B-fragment order:
// hB[kb][nb][lane][i] = bf16( h[kb*32 + (lane>>4)*8 + i][nb*16 + (lane&15)] )
// ---------------------------------------------------------------------------
__global__ __launch_bounds__(256) void swizzle_kernel(
    const float* __restrict__ h, short* __restrict__ hB,
    int nblk, int ncols, int total)
{
    int tid = blockIdx.x * 256 + threadIdx.x;
    if (tid >= total) return;
    int i  = tid & 7;
    int l  = (tid >> 3) & 63;
    int t2 = tid >> 9;
    int nb = t2 % nblk;
    int kb = t2 / nblk;
    int row = kb * 32 + (l >> 4) * 8 + i;
    int col = nb * 16 + (l & 15);
    float v = h[(size_t)row * ncols + col];
    hB[tid] = (short)f2bfu(v);
}

// ---------------------------------------------------------------------------
// FUSED GAT layer. Block = 16 waves x 1024 thr (LB(1024,8) -> VGPR<=64,
// 2 blocks/CU -> 32 waves/CU). Wave owns mb (16 rows) x seg (16 kb).
// B-slice + Es staged in LDS once. K-loop: 2 clean f32 adj line-loads,
// LDS e-reads, sigmoid VALU, shuffle-to-fragment, NBLK MFMAs.
// NO global stores in the loop (870 GB/s trap, r5/r6/r11).
// ---------------------------------------------------------------------------
template <int NBLK>
__global__ __launch_bounds__(1024, 8) void fused_kernel(
    const float* __restrict__ adj, const float* __restrict__ fsrc,
    const float* __restrict__ edst, const short* __restrict__ Bfrag,
    float* __restrict__ outp, float* __restrict__ normpart)
{
    __shared__ __align__(16) short Bs[16 * NBLK * 64 * 8];  // 64KB / 16KB
    __shared__ __align__(16) float Es[512];                 // 2KB
    const int tid  = threadIdx.x;
    const int lane = tid & 63;
    const int w    = tid >> 6;          // 0..15
    const int seg  = blockIdx.y;
    const int mb   = blockIdx.x * 16 + w;

    {
        const short8* src = (const short8*)(Bfrag) + (size_t)seg * (16 * NBLK * 64);
        short8* dst = (short8*)Bs;
#pragma unroll
        for (int j = 0; j < NBLK; ++j)
            dst[tid + 1024 * j] = src[tid + 1024 * j];
        if (tid < 512) Es[tid] = edst[seg * 512 + tid];
    }
    __syncthreads();

    const int r = lane >> 2;       // load-layout row 0..15
    const int q = lane & 3;        // load-layout col quarter

    const float F_i = fsrc[mb * 16 + r];
    const float* arow = adj + (size_t)(mb * 16 + r) * NN;

    // fragment-lane coordinates (destination of the permute)
    const int fg = lane >> 4;
    const int fr = lane & 15;
    const int s0 = fr * 4 + (fg & 1) * 2;
    const int s1 = s0 + 1;
    const bool lowhalf = (fg < 2);

    f32x4 acc[NBLK];
#pragma unroll
    for (int nb = 0; nb < NBLK; ++nb) acc[nb] = (f32x4){0.f, 0.f, 0.f, 0.f};
    float nacc = 0.f;

    for (int k = 0; k < 16; ++k) {
        const int col0 = (seg * 16 + k) * 32;
        f32x4 a0 = *(const f32x4*)(arow + col0 + q * 4);
        f32x4 a1 = *(const f32x4*)(arow + col0 + 16 + q * 4);
        f32x4 e0 = *(const f32x4*)&Es[k * 32 + q * 4];
        f32x4 e1 = *(const f32x4*)&Es[k * 32 + 16 + q * 4];

        float v[8];
#pragma unroll
        for (int t = 0; t < 4; ++t) {
            float sg  = __builtin_amdgcn_rcpf(fmaf(F_i, e0[t], 1.0f));
            float att = sg * a0[t];
            nacc = fmaf(att, att, nacc);
            v[t] = att;
        }
#pragma unroll
        for (int t = 0; t < 4; ++t) {
            float sg  = __builtin_amdgcn_rcpf(fmaf(F_i, e1[t], 1.0f));
            float att = sg * a1[t];
            nacc = fmaf(att, att, nacc);
            v[4 + t] = att;
        }
        int d0 = (int)(f2bfu(v[0]) | (f2bfu(v[1]) << 16));
        int d1 = (int)(f2bfu(v[2]) | (f2bfu(v[3]) << 16));
        int d2 = (int)(f2bfu(v[4]) | (f2bfu(v[5]) << 16));
        int d3 = (int)(f2bfu(v[6]) | (f2bfu(v[7]) << 16));

        int p00 = __shfl(d0, s0, 64), p01 = __shfl(d1, s0, 64);
        int p10 = __shfl(d0, s1, 64), p11 = __shfl(d1, s1, 64);
        int q00 = __shfl(d2, s0, 64), q01 = __shfl(d3, s0, 64);
        int q10 = __shfl(d2, s1, 64), q11 = __shfl(d3, s1, 64);
        i32x4 wv;
        wv[0] = lowhalf ? p00 : q00;
        wv[1] = lowhalf ? p01 : q01;
        wv[2] = lowhalf ? p10 : q10;
        wv[3] = lowhalf ? p11 : q11;
        short8 af = *(short8*)&wv;

#pragma unroll
        for (int nb = 0; nb < NBLK; ++nb) {
            short8 bf = *(const short8*)&Bs[((k * NBLK + nb) * 64 + lane) * 8];
            acc[nb] = __builtin_amdgcn_mfma_f32_16x16x32_bf16(af, bf, acc[nb], 0, 0, 0);
        }
    }

    // norm partial: lanes r*4..r*4+3 hold row r pieces
    nacc += __shfl_xor(nacc, 1);
    nacc += __shfl_xor(nacc, 2);
    if (q == 0) normpart[(mb * 16 + r) * 16 + seg] = nacc;

    // C/D: col = lane&15, row = (lane>>4)*4 + rr
    constexpr int F = NBLK * 16;
#pragma unroll
    for (int nb = 0; nb < NBLK; ++nb)
#pragma unroll
        for (int rr = 0; rr < 4; ++rr)
            outp[((size_t)seg * NN + mb * 16 + fg * 4 + rr) * F + nb * 16 + fr]
                = acc[nb][rr];
}

// ---------------------------------------------------------------------------
// R1: h1[i][f] = sum_seg outp1 / (sqrt(sum_p normpart1[i][p]) + 1e-10)
// ---------------------------------------------------------------------------
__global__ __launch_bounds__(256) void r1_kernel(
    const float* __restrict__ outp, const float* __restrict__ normpart,
    float* __restrict__ h1)
{
    int tid = blockIdx.x * 256 + threadIdx.x;
    int i = tid >> 6, f = tid & 63;
    float s = 0.f;
#pragma unroll
    for (int sg = 0; sg < 16; ++sg)
        s += outp[((size_t)sg * NN + i) * 64 + f];
    float n = 0.f;
#pragma unroll
    for (int p = 0; p < 16; ++p) n += normpart[i * 16 + p];
    h1[tid] = s / (sqrtf(n) + 1e-10f);
}

// ---------------------------------------------------------------------------
// P2: z = h1 @ W2 (padded to 16 cols), fsrc2/edst2 = exp(-z . a2 halves)
// ---------------------------------------------------------------------------
__global__ __launch_bounds__(256) void p2_kernel(
    const float* __restrict__ h1, const float* __restrict__ W2,
    const float* __restrict__ a2, float* __restrict__ z,
    float* __restrict__ fsrc2, float* __restrict__ edst2)
{
    int i = blockIdx.x * 256 + threadIdx.x;
    if (i >= NN) return;
    float zz[10];
#pragma unroll
    for (int c = 0; c < 10; ++c) zz[c] = 0.f;
    for (int f = 0; f < 64; ++f) {
        float hv = h1[(size_t)i * 64 + f];
#pragma unroll
        for (int c = 0; c < 10; ++c) zz[c] = fmaf(hv, W2[f * 10 + c], zz[c]);
    }
    float s1 = 0.f, s2 = 0.f;
#pragma unroll
    for (int c = 0; c < 10; ++c) {
        s1 = fmaf(zz[c], a2[c], s1);
        s2 = fmaf(zz[c], a2[10 + c], s2);
        z[(size_t)i * 16 + c] = zz[c];
    }
#pragma unroll
    for (int c = 10; c < 16; ++c) z[(size_t)i * 16 + c] = 0.f;
    fsrc2[i] = expneg(s1);
    edst2[i] = expneg(s2);
}

// ---------------------------------------------------------------------------
// R2: h2 = partials/norm, then log_softmax over 10 classes -> d_out
// ---------------------------------------------------------------------------
__global__ __launch_bounds__(256) void r2_kernel(
    const float* __restrict__ outp, const float* __restrict__ normpart,
    float* __restrict__ out)
{
    int i = blockIdx.x * 256 + threadIdx.x;
    if (i >= NN) return;
    float n = 0.f;
#pragma unroll
    for (int p = 0; p < 16; ++p) n += normpart[i * 16 + p];
    float inv = 1.0f / (sqrtf(n) + 1e-10f);
    float v[10];
    float m = -1e30f;
#pragma unroll
    for (int c = 0; c < 10; ++c) {
        float s = 0.f;
#pragma unroll
        for (int sg = 0; sg < 16; ++sg)
            s += outp[((size_t)sg * NN + i) * 16 + c];
        v[c] = s * inv;
        m = fmaxf(m, v[c]);
    }
    float es = 0.f;
#pragma unroll
    for (int c = 0; c < 10; ++c) es += expf(v[c] - m);
    float lse = m + logf(es);
#pragma unroll
    for (int c = 0; c < 10; ++c) out[(size_t)i * 10 + c] = v[c] - lse;
}

extern "C" void kernel_launch(void* const* d_in, const int* in_sizes, int n_in,
                              void* d_out, int out_size, void* d_ws, size_t ws_size,
                              hipStream_t stream)
{
    const float* x   = (const float*)d_in[0];
    const float* adj = (const float*)d_in[1];
    const float* W1  = (const float*)d_in[2];
    const float* a1  = (const float*)d_in[3];
    const float* W2  = (const float*)d_in[4];
    const float* a2  = (const float*)d_in[5];
    float* out = (float*)d_out;

    char* ws = (char*)d_ws;
    size_t off = 0;
    auto alloc = [&](size_t bytes) -> void* {
        void* p = ws + off;
        off += (bytes + 255) & ~(size_t)255;
        return p;
    };
    float* h      = (float*)alloc((size_t)NN * 64 * 4);
    float* fsrc1  = (float*)alloc((size_t)NN * 4);
    float* edst1  = (float*)alloc((size_t)NN * 4);
    short* hB1    = (short*)alloc((size_t)NN * 64 * 2);
    float* outp1  = (float*)alloc((size_t)16 * NN * 64 * 4);     // 33.5MB
    float* normp1 = (float*)alloc((size_t)NN * 16 * 4);
    float* h1     = (float*)alloc((size_t)NN * 64 * 4);
    float* z      = (float*)alloc((size_t)NN * 16 * 4);
    float* fsrc2  = (float*)alloc((size_t)NN * 4);
    float* edst2  = (float*)alloc((size_t)NN * 4);
    short* zB     = (short*)alloc((size_t)NN * 16 * 2);
    float* outp2  = (float*)alloc((size_t)16 * NN * 16 * 4);     // 8.4MB
    float* normp2 = (float*)alloc((size_t)NN * 16 * 4);

    hipLaunchKernelGGL(p1_kernel, dim3(NN / 16), dim3(256), 0, stream,
                       x, W1, a1, h, fsrc1, edst1);
    hipLaunchKernelGGL(swizzle_kernel, dim3(2048), dim3(256), 0, stream,
                       h, hB1, 4, 64, NN * 64);
    hipLaunchKernelGGL((fused_kernel<4>), dim3(32, 16), dim3(1024), 0, stream,
                       adj, fsrc1, edst1, hB1, outp1, normp1);
    hipLaunchKernelGGL(r1_kernel, dim3(2048), dim3(256), 0, stream,
                       outp1, normp1, h1);
    hipLaunchKernelGGL(p2_kernel, dim3(32), dim3(256), 0, stream,
                       h1, W2, a2, z, fsrc2, edst2);
    hipLaunchKernelGGL(swizzle_kernel, dim3(512), dim3(256), 0, stream,
                       z, zB, 1, 16, NN * 16);
    hipLaunchKernelGGL((fused_kernel<1>), dim3(32, 16), dim3(1024), 0, stream,
                       adj, fsrc2, edst2, zB, outp2, normp2);
    hipLaunchKernelGGL(r2_kernel, dim3(32), dim3(256), 0, stream,
                       outp2, normp2, out);
}

// Round 13
// 186.790 us; speedup vs baseline: 1.2526x; 1.0457x over previous
//
#include <hip/hip_runtime.h>
#include <hip/hip_bf16.h>
#include <math.h>

typedef __attribute__((ext_vector_type(4))) float f32x4;
typedef __attribute__((ext_vector_type(4))) int   i32x4;
typedef __attribute__((ext_vector_type(8))) short short8;

#define NN 8192
#define LOG2E 1.44269504088896f

// f32 -> bf16 bits, round-to-nearest-even
__device__ __forceinline__ unsigned f2bfu(float x) {
    unsigned u = __float_as_uint(x);
    u += 0x7FFFu + ((u >> 16) & 1u);
    return u >> 16;
}
__device__ __forceinline__ float expneg(float s) {   // exp(-s)
    return __builtin_amdgcn_exp2f(-LOG2E * s);
}

// ---------------------------------------------------------------------------
// P1: h = x @ W1  [8192,500]@[500,64] with W1 staged in LDS. 1024 blocks x
// 8 rows (2 rows/wave) -> 16 waves/CU. Writes fsrc/edst = exp(-h.a halves).
// ---------------------------------------------------------------------------
#define P1_CHUNK 100
__global__ __launch_bounds__(256) void p1_kernel(
    const float* __restrict__ x, const float* __restrict__ W1,
    const float* __restrict__ a1, float* __restrict__ h,
    float* __restrict__ fsrc, float* __restrict__ edst)
{
    __shared__ float wtile[P1_CHUNK * 64];
    const int lane = threadIdx.x & 63;
    const int w    = threadIdx.x >> 6;
    const int r0   = blockIdx.x * 8 + w * 2;

    float acc[2];
    acc[0] = 0.f; acc[1] = 0.f;

    for (int c = 0; c < 5; ++c) {
        const int kb = c * P1_CHUNK;
        __syncthreads();
        for (int idx = threadIdx.x; idx < P1_CHUNK * 64; idx += 256)
            wtile[idx] = W1[kb * 64 + idx];
        __syncthreads();
        for (int kk = 0; kk < P1_CHUNK; kk += 4) {
            float w0 = wtile[(kk + 0) * 64 + lane];
            float w1 = wtile[(kk + 1) * 64 + lane];
            float w2 = wtile[(kk + 2) * 64 + lane];
            float w3 = wtile[(kk + 3) * 64 + lane];
#pragma unroll
            for (int r = 0; r < 2; ++r) {
                f32x4 xv = *(const f32x4*)(x + (size_t)(r0 + r) * 500 + kb + kk);
                acc[r] = fmaf(xv[0], w0, acc[r]);
                acc[r] = fmaf(xv[1], w1, acc[r]);
                acc[r] = fmaf(xv[2], w2, acc[r]);
                acc[r] = fmaf(xv[3], w3, acc[r]);
            }
        }
    }
    float a_s = a1[lane], a_d = a1[64 + lane];
#pragma unroll
    for (int r = 0; r < 2; ++r) {
        h[(size_t)(r0 + r) * 64 + lane] = acc[r];
        float ps = acc[r] * a_s, pd = acc[r] * a_d;
        for (int off = 32; off > 0; off >>= 1) {
            ps += __shfl_down(ps, off); pd += __shfl_down(pd, off);
        }
        if (lane == 0) {
            fsrc[r0 + r] = expneg(ps);
            edst[r0 + r] = expneg(pd);
        }
    }
}

// ---------------------------------------------------------------------------
// Swizzle f32 matrix into bf16 B-fragment order:
// hB[kb][nb][lane][i] = bf16( h[kb*32 + (lane>>4)*8 + i][nb*16 + (lane&15)] )
// ---------------------------------------------------------------------------
__global__ __launch_bounds__(256) void swizzle_kernel(
    const float* __restrict__ h, short* __restrict__ hB,
    int nblk, int ncols, int total)
{
    int tid = blockIdx.x * 256 + threadIdx.x;
    if (tid >= total) return;
    int i  = tid & 7;
    int l  = (tid >> 3) & 63;
    int t2 = tid >> 9;
    int nb = t2 % nblk;
    int kb = t2 / nblk;
    int row = kb * 32 + (l >> 4) * 8 + i;
    int col = nb * 16 + (l & 15);
    float v = h[(size_t)row * ncols + col];
    hB[tid] = (short)f2bfu(v);
}

// ---------------------------------------------------------------------------
// FUSED GAT layer. Block = 16 waves x 1024 thr (LB(1024,8) -> VGPR<=64,
// 2 blocks/CU -> 32 waves/CU). Wave owns mb (16 rows) x seg (16 kb).
// B-slice + Es staged in LDS once. K-loop: DEPTH-1 SOFTWARE-PIPELINED
// clean f32 adj line-loads (prefetch k+1 before computing k), LDS e-reads,
// sigmoid VALU, shuffle-to-fragment, NBLK MFMAs.
// NO global stores in the loop (870 GB/s trap, r5/r6/r11).
// ---------------------------------------------------------------------------
template <int NBLK>
__global__ __launch_bounds__(1024, 8) void fused_kernel(
    const float* __restrict__ adj, const float* __restrict__ fsrc,
    const float* __restrict__ edst, const short* __restrict__ Bfrag,
    float* __restrict__ outp, float* __restrict__ normpart)
{
    __shared__ __align__(16) short Bs[16 * NBLK * 64 * 8];  // 64KB / 16KB
    __shared__ __align__(16) float Es[512];                 // 2KB
    const int tid  = threadIdx.x;
    const int lane = tid & 63;
    const int w    = tid >> 6;          // 0..15
    const int seg  = blockIdx.y;
    const int mb   = blockIdx.x * 16 + w;

    {
        const short8* src = (const short8*)(Bfrag) + (size_t)seg * (16 * NBLK * 64);
        short8* dst = (short8*)Bs;
#pragma unroll
        for (int j = 0; j < NBLK; ++j)
            dst[tid + 1024 * j] = src[tid + 1024 * j];
        if (tid < 512) Es[tid] = edst[seg * 512 + tid];
    }
    __syncthreads();

    const int r = lane >> 2;       // load-layout row 0..15
    const int q = lane & 3;        // load-layout col quarter

    const float F_i = fsrc[mb * 16 + r];
    const float* arow = adj + (size_t)(mb * 16 + r) * NN + (size_t)seg * 512 + q * 4;

    // fragment-lane coordinates (destination of the permute)
    const int fg = lane >> 4;
    const int fr = lane & 15;
    const int s0 = fr * 4 + (fg & 1) * 2;
    const int s1 = s0 + 1;
    const bool lowhalf = (fg < 2);

    f32x4 acc[NBLK];
#pragma unroll
    for (int nb = 0; nb < NBLK; ++nb) acc[nb] = (f32x4){0.f, 0.f, 0.f, 0.f};
    float nacc = 0.f;

    // depth-1 software pipeline on the adj loads
    f32x4 a0c = *(const f32x4*)(arow);
    f32x4 a1c = *(const f32x4*)(arow + 16);

    for (int k = 0; k < 16; ++k) {
        f32x4 a0n, a1n;
        if (k < 15) {
            a0n = *(const f32x4*)(arow + (k + 1) * 32);
            a1n = *(const f32x4*)(arow + (k + 1) * 32 + 16);
        }
        f32x4 e0 = *(const f32x4*)&Es[k * 32 + q * 4];
        f32x4 e1 = *(const f32x4*)&Es[k * 32 + 16 + q * 4];

        float v[8];
#pragma unroll
        for (int t = 0; t < 4; ++t) {
            float sg  = __builtin_amdgcn_rcpf(fmaf(F_i, e0[t], 1.0f));
            float att = sg * a0c[t];
            nacc = fmaf(att, att, nacc);
            v[t] = att;
        }
#pragma unroll
        for (int t = 0; t < 4; ++t) {
            float sg  = __builtin_amdgcn_rcpf(fmaf(F_i, e1[t], 1.0f));
            float att = sg * a1c[t];
            nacc = fmaf(att, att, nacc);
            v[4 + t] = att;
        }
        int d0 = (int)(f2bfu(v[0]) | (f2bfu(v[1]) << 16));
        int d1 = (int)(f2bfu(v[2]) | (f2bfu(v[3]) << 16));
        int d2 = (int)(f2bfu(v[4]) | (f2bfu(v[5]) << 16));
        int d3 = (int)(f2bfu(v[6]) | (f2bfu(v[7]) << 16));

        int p00 = __shfl(d0, s0, 64), p01 = __shfl(d1, s0, 64);
        int p10 = __shfl(d0, s1, 64), p11 = __shfl(d1, s1, 64);
        int q00 = __shfl(d2, s0, 64), q01 = __shfl(d3, s0, 64);
        int q10 = __shfl(d2, s1, 64), q11 = __shfl(d3, s1, 64);
        i32x4 wv;
        wv[0] = lowhalf ? p00 : q00;
        wv[1] = lowhalf ? p01 : q01;
        wv[2] = lowhalf ? p10 : q10;
        wv[3] = lowhalf ? p11 : q11;
        short8 af = *(short8*)&wv;

#pragma unroll
        for (int nb = 0; nb < NBLK; ++nb) {
            short8 bf = *(const short8*)&Bs[((k * NBLK + nb) * 64 + lane) * 8];
            acc[nb] = __builtin_amdgcn_mfma_f32_16x16x32_bf16(af, bf, acc[nb], 0, 0, 0);
        }
        a0c = a0n; a1c = a1n;
    }

    // norm partial: lanes r*4..r*4+3 hold row r pieces
    nacc += __shfl_xor(nacc, 1);
    nacc += __shfl_xor(nacc, 2);
    if (q == 0) normpart[(mb * 16 + r) * 16 + seg] = nacc;

    // C/D: col = lane&15, row = (lane>>4)*4 + rr
    constexpr int F = NBLK * 16;
#pragma unroll
    for (int nb = 0; nb < NBLK; ++nb)
#pragma unroll
        for (int rr = 0; rr < 4; ++rr)
            outp[((size_t)seg * NN + mb * 16 + fg * 4 + rr) * F + nb * 16 + fr]
                = acc[nb][rr];
}

// ---------------------------------------------------------------------------
// R1: h1[i][f] = sum_seg outp1 / (sqrt(sum_p normpart1[i][p]) + 1e-10)
// ---------------------------------------------------------------------------
__global__ __launch_bounds__(256) void r1_kernel(
    const float* __restrict__ outp, const float* __restrict__ normpart,
    float* __restrict__ h1)
{
    int tid = blockIdx.x * 256 + threadIdx.x;
    int i = tid >> 6, f = tid & 63;
    float s = 0.f;
#pragma unroll
    for (int sg = 0; sg < 16; ++sg)
        s += outp[((size_t)sg * NN + i) * 64 + f];
    float n = 0.f;
#pragma unroll
    for (int p = 0; p < 16; ++p) n += normpart[i * 16 + p];
    h1[tid] = s / (sqrtf(n) + 1e-10f);
}

// ---------------------------------------------------------------------------
// P2: z = h1 @ W2 (padded to 16 cols), fsrc2/edst2 = exp(-z . a2 halves)
// ---------------------------------------------------------------------------
__global__ __launch_bounds__(256) void p2_kernel(
    const float* __restrict__ h1, const float* __restrict__ W2,
    const float* __restrict__ a2, float* __restrict__ z,
    float* __restrict__ fsrc2, float* __restrict__ edst2)
{
    int i = blockIdx.x * 256 + threadIdx.x;
    if (i >= NN) return;
    float zz[10];
#pragma unroll
    for (int c = 0; c < 10; ++c) zz[c] = 0.f;
    for (int f = 0; f < 64; ++f) {
        float hv = h1[(size_t)i * 64 + f];
#pragma unroll
        for (int c = 0; c < 10; ++c) zz[c] = fmaf(hv, W2[f * 10 + c], zz[c]);
    }
    float s1 = 0.f, s2 = 0.f;
#pragma unroll
    for (int c = 0; c < 10; ++c) {
        s1 = fmaf(zz[c], a2[c], s1);
        s2 = fmaf(zz[c], a2[10 + c], s2);
        z[(size_t)i * 16 + c] = zz[c];
    }
#pragma unroll
    for (int c = 10; c < 16; ++c) z[(size_t)i * 16 + c] = 0.f;
    fsrc2[i] = expneg(s1);
    edst2[i] = expneg(s2);
}

// ---------------------------------------------------------------------------
// R2: h2 = partials/norm, then log_softmax over 10 classes -> d_out
// ---------------------------------------------------------------------------
__global__ __launch_bounds__(256) void r2_kernel(
    const float* __restrict__ outp, const float* __restrict__ normpart,
    float* __restrict__ out)
{
    int i = blockIdx.x * 256 + threadIdx.x;
    if (i >= NN) return;
    float n = 0.f;
#pragma unroll
    for (int p = 0; p < 16; ++p) n += normpart[i * 16 + p];
    float inv = 1.0f / (sqrtf(n) + 1e-10f);
    float v[10];
    float m = -1e30f;
#pragma unroll
    for (int c = 0; c < 10; ++c) {
        float s = 0.f;
#pragma unroll
        for (int sg = 0; sg < 16; ++sg)
            s += outp[((size_t)sg * NN + i) * 16 + c];
        v[c] = s * inv;
        m = fmaxf(m, v[c]);
    }
    float es = 0.f;
#pragma unroll
    for (int c = 0; c < 10; ++c) es += expf(v[c] - m);
    float lse = m + logf(es);
#pragma unroll
    for (int c = 0; c < 10; ++c) out[(size_t)i * 10 + c] = v[c] - lse;
}

extern "C" void kernel_launch(void* const* d_in, const int* in_sizes, int n_in,
                              void* d_out, int out_size, void* d_ws, size_t ws_size,
                              hipStream_t stream)
{
    const float* x   = (const float*)d_in[0];
    const float* adj = (const float*)d_in[1];
    const float* W1  = (const float*)d_in[2];
    const float* a1  = (const float*)d_in[3];
    const float* W2  = (const float*)d_in[4];
    const float* a2  = (const float*)d_in[5];
    float* out = (float*)d_out;

    char* ws = (char*)d_ws;
    size_t off = 0;
    auto alloc = [&](size_t bytes) -> void* {
        void* p = ws + off;
        off += (bytes + 255) & ~(size_t)255;
        return p;
    };
    float* h      = (float*)alloc((size_t)NN * 64 * 4);
    float* fsrc1  = (float*)alloc((size_t)NN * 4);
    float* edst1  = (float*)alloc((size_t)NN * 4);
    short* hB1    = (short*)alloc((size_t)NN * 64 * 2);
    float* outp1  = (float*)alloc((size_t)16 * NN * 64 * 4);     // 33.5MB
    float* normp1 = (float*)alloc((size_t)NN * 16 * 4);
    float* h1     = (float*)alloc((size_t)NN * 64 * 4);
    float* z      = (float*)alloc((size_t)NN * 16 * 4);
    float* fsrc2  = (float*)alloc((size_t)NN * 4);
    float* edst2  = (float*)alloc((size_t)NN * 4);
    short* zB     = (short*)alloc((size_t)NN * 16 * 2);
    float* outp2  = (float*)alloc((size_t)16 * NN * 16 * 4);     // 8.4MB
    float* normp2 = (float*)alloc((size_t)NN * 16 * 4);

    hipLaunchKernelGGL(p1_kernel, dim3(NN / 8), dim3(256), 0, stream,
                       x, W1, a1, h, fsrc1, edst1);
    hipLaunchKernelGGL(swizzle_kernel, dim3(2048), dim3(256), 0, stream,
                       h, hB1, 4, 64, NN * 64);
    hipLaunchKernelGGL((fused_kernel<4>), dim3(32, 16), dim3(1024), 0, stream,
                       adj, fsrc1, edst1, hB1, outp1, normp1);
    hipLaunchKernelGGL(r1_kernel, dim3(2048), dim3(256), 0, stream,
                       outp1, normp1, h1);
    hipLaunchKernelGGL(p2_kernel, dim3(32), dim3(256), 0, stream,
                       h1, W2, a2, z, fsrc2, edst2);
    hipLaunchKernelGGL(swizzle_kernel, dim3(512), dim3(256), 0, stream,
                       z, zB, 1, 16, NN * 16);
    hipLaunchKernelGGL((fused_kernel<1>), dim3(32, 16), dim3(1024), 0, stream,
                       adj, fsrc2, edst2, zB, outp2, normp2);
    hipLaunchKernelGGL(r2_kernel, dim3(32), dim3(256), 0, stream,
                       outp2, normp2, out);
}

// Round 14
// 179.432 us; speedup vs baseline: 1.3040x; 1.0410x over previous
//
#include <hip/hip_runtime.h>
#include <hip/hip_bf16.h>
#include <math.h>

typedef __attribute__((ext_vector_type(4))) float f32x4;
typedef __attribute__((ext_vector_type(4))) int   i32x4;
typedef __attribute__((ext_vector_type(8))) short short8;

#define NN 8192
#define LOG2E 1.44269504088896f

// f32 -> bf16 bits, round-to-nearest-even
__device__ __forceinline__ unsigned f2bfu(float x) {
    unsigned u = __float_as_uint(x);
    u += 0x7FFFu + ((u >> 16) & 1u);
    return u >> 16;
}
__device__ __forceinline__ float expneg(float s) {   // exp(-s)
    return __builtin_amdgcn_exp2f(-LOG2E * s);
}

// ---------------------------------------------------------------------------
// P1: h = x @ W1  [8192,500]@[500,64] with W1 staged in LDS. 1024 blocks x
// 8 rows (2 rows/wave) -> 16 waves/CU. Writes fsrc/edst = exp(-h.a halves).
// ---------------------------------------------------------------------------
#define P1_CHUNK 100
__global__ __launch_bounds__(256) void p1_kernel(
    const float* __restrict__ x, const float* __restrict__ W1,
    const float* __restrict__ a1, float* __restrict__ h,
    float* __restrict__ fsrc, float* __restrict__ edst)
{
    __shared__ float wtile[P1_CHUNK * 64];
    const int lane = threadIdx.x & 63;
    const int w    = threadIdx.x >> 6;
    const int r0   = blockIdx.x * 8 + w * 2;

    float acc[2];
    acc[0] = 0.f; acc[1] = 0.f;

    for (int c = 0; c < 5; ++c) {
        const int kb = c * P1_CHUNK;
        __syncthreads();
        for (int idx = threadIdx.x; idx < P1_CHUNK * 64; idx += 256)
            wtile[idx] = W1[kb * 64 + idx];
        __syncthreads();
        for (int kk = 0; kk < P1_CHUNK; kk += 4) {
            float w0 = wtile[(kk + 0) * 64 + lane];
            float w1 = wtile[(kk + 1) * 64 + lane];
            float w2 = wtile[(kk + 2) * 64 + lane];
            float w3 = wtile[(kk + 3) * 64 + lane];
#pragma unroll
            for (int r = 0; r < 2; ++r) {
                f32x4 xv = *(const f32x4*)(x + (size_t)(r0 + r) * 500 + kb + kk);
                acc[r] = fmaf(xv[0], w0, acc[r]);
                acc[r] = fmaf(xv[1], w1, acc[r]);
                acc[r] = fmaf(xv[2], w2, acc[r]);
                acc[r] = fmaf(xv[3], w3, acc[r]);
            }
        }
    }
    float a_s = a1[lane], a_d = a1[64 + lane];
#pragma unroll
    for (int r = 0; r < 2; ++r) {
        h[(size_t)(r0 + r) * 64 + lane] = acc[r];
        float ps = acc[r] * a_s, pd = acc[r] * a_d;
        for (int off = 32; off > 0; off >>= 1) {
            ps += __shfl_down(ps, off); pd += __shfl_down(pd, off);
        }
        if (lane == 0) {
            fsrc[r0 + r] = expneg(ps);
            edst[r0 + r] = expneg(pd);
        }
    }
}

// ---------------------------------------------------------------------------
// Swizzle f32 matrix into bf16 B-fragment order (layer-1 h -> hB):
// hB[kb][nb][lane][i] = bf16( h[kb*32 + (lane>>4)*8 + i][nb*16 + (lane&15)] )
// ---------------------------------------------------------------------------
__global__ __launch_bounds__(256) void swizzle_kernel(
    const float* __restrict__ h, short* __restrict__ hB,
    int nblk, int ncols, int total)
{
    int tid = blockIdx.x * 256 + threadIdx.x;
    if (tid >= total) return;
    int i  = tid & 7;
    int l  = (tid >> 3) & 63;
    int t2 = tid >> 9;
    int nb = t2 % nblk;
    int kb = t2 / nblk;
    int row = kb * 32 + (l >> 4) * 8 + i;
    int col = nb * 16 + (l & 15);
    float v = h[(size_t)row * ncols + col];
    hB[tid] = (short)f2bfu(v);
}

// ---------------------------------------------------------------------------
// FUSED GAT layer, 2-MB-PER-WAVE. Block = 8 waves x 512 thr, LB(512,4)
// (VGPR<=128, 16 waves/CU). Wave owns TWO 16-row tiles (mb0, mb0+1) x seg.
// Per k-step: Es reads (2xb128) and B-frag reads (NBLKxb128) are SHARED by
// both tiles -> LDS-pipe cost per KB of adj nearly halves (the r13 4.4TB/s
// LDS ceiling -> ~6.3TB/s). Depth-1 prefetch on all 4 adj loads.
// NO global stores in the loop (870 GB/s trap).
// ---------------------------------------------------------------------------
template <int NBLK>
__global__ __launch_bounds__(512, 4) void fused_kernel(
    const float* __restrict__ adj, const float* __restrict__ fsrc,
    const float* __restrict__ edst, const short* __restrict__ Bfrag,
    float* __restrict__ outp, float* __restrict__ normpart)
{
    __shared__ __align__(16) short Bs[16 * NBLK * 64 * 8];  // 64KB / 16KB
    __shared__ __align__(16) float Es[512];                 // 2KB
    const int tid  = threadIdx.x;
    const int lane = tid & 63;
    const int w    = tid >> 6;          // 0..7
    const int seg  = blockIdx.y;
    const int mb0  = blockIdx.x * 16 + w * 2;

    {
        const short8* src = (const short8*)(Bfrag) + (size_t)seg * (16 * NBLK * 64);
        short8* dst = (short8*)Bs;
#pragma unroll
        for (int j = 0; j < 2 * NBLK; ++j)
            dst[tid + 512 * j] = src[tid + 512 * j];
        Es[tid] = edst[seg * 512 + tid];
    }
    __syncthreads();

    const int r = lane >> 2;       // load-layout row 0..15
    const int q = lane & 3;        // load-layout col quarter

    const float F0 = fsrc[mb0 * 16 + r];
    const float F1 = fsrc[mb0 * 16 + 16 + r];
    const float* ar0 = adj + (size_t)(mb0 * 16 + r) * NN + (size_t)seg * 512 + q * 4;
    const float* ar1 = ar0 + (size_t)16 * NN;

    // fragment-lane coordinates (destination of the permute)
    const int fg = lane >> 4;
    const int fr = lane & 15;
    const int s0 = fr * 4 + (fg & 1) * 2;
    const int s1 = s0 + 1;
    const bool lowhalf = (fg < 2);

    f32x4 acc[2][NBLK];
#pragma unroll
    for (int m = 0; m < 2; ++m)
#pragma unroll
        for (int nb = 0; nb < NBLK; ++nb) acc[m][nb] = (f32x4){0.f, 0.f, 0.f, 0.f};
    float nacc0 = 0.f, nacc1 = 0.f;

    // att+pack+permute -> A-fragment for one 16-row tile
    auto mkfrag = [&](f32x4 a0, f32x4 a1, f32x4 e0, f32x4 e1, float F_i,
                      float& nacc) -> short8 {
        float v[8];
#pragma unroll
        for (int t = 0; t < 4; ++t) {
            float sg  = __builtin_amdgcn_rcpf(fmaf(F_i, e0[t], 1.0f));
            float att = sg * a0[t];
            nacc = fmaf(att, att, nacc);
            v[t] = att;
        }
#pragma unroll
        for (int t = 0; t < 4; ++t) {
            float sg  = __builtin_amdgcn_rcpf(fmaf(F_i, e1[t], 1.0f));
            float att = sg * a1[t];
            nacc = fmaf(att, att, nacc);
            v[4 + t] = att;
        }
        int d0 = (int)(f2bfu(v[0]) | (f2bfu(v[1]) << 16));
        int d1 = (int)(f2bfu(v[2]) | (f2bfu(v[3]) << 16));
        int d2 = (int)(f2bfu(v[4]) | (f2bfu(v[5]) << 16));
        int d3 = (int)(f2bfu(v[6]) | (f2bfu(v[7]) << 16));
        int p00 = __shfl(d0, s0, 64), p01 = __shfl(d1, s0, 64);
        int p10 = __shfl(d0, s1, 64), p11 = __shfl(d1, s1, 64);
        int q00 = __shfl(d2, s0, 64), q01 = __shfl(d3, s0, 64);
        int q10 = __shfl(d2, s1, 64), q11 = __shfl(d3, s1, 64);
        i32x4 wv;
        wv[0] = lowhalf ? p00 : q00;
        wv[1] = lowhalf ? p01 : q01;
        wv[2] = lowhalf ? p10 : q10;
        wv[3] = lowhalf ? p11 : q11;
        return *(short8*)&wv;
    };

    // depth-1 software pipeline on all 4 adj loads
    f32x4 c00 = *(const f32x4*)(ar0);
    f32x4 c01 = *(const f32x4*)(ar0 + 16);
    f32x4 c10 = *(const f32x4*)(ar1);
    f32x4 c11 = *(const f32x4*)(ar1 + 16);

    for (int k = 0; k < 16; ++k) {
        f32x4 n00, n01, n10, n11;
        if (k < 15) {
            n00 = *(const f32x4*)(ar0 + (k + 1) * 32);
            n01 = *(const f32x4*)(ar0 + (k + 1) * 32 + 16);
            n10 = *(const f32x4*)(ar1 + (k + 1) * 32);
            n11 = *(const f32x4*)(ar1 + (k + 1) * 32 + 16);
        }
        f32x4 e0 = *(const f32x4*)&Es[k * 32 + q * 4];
        f32x4 e1 = *(const f32x4*)&Es[k * 32 + 16 + q * 4];

        short8 af0 = mkfrag(c00, c01, e0, e1, F0, nacc0);
        short8 af1 = mkfrag(c10, c11, e0, e1, F1, nacc1);

#pragma unroll
        for (int nb = 0; nb < NBLK; ++nb) {
            short8 bf = *(const short8*)&Bs[((k * NBLK + nb) * 64 + lane) * 8];
            acc[0][nb] = __builtin_amdgcn_mfma_f32_16x16x32_bf16(af0, bf, acc[0][nb], 0, 0, 0);
            acc[1][nb] = __builtin_amdgcn_mfma_f32_16x16x32_bf16(af1, bf, acc[1][nb], 0, 0, 0);
        }
        c00 = n00; c01 = n01; c10 = n10; c11 = n11;
    }

    // norm partials: lanes r*4..r*4+3 hold row r pieces
    nacc0 += __shfl_xor(nacc0, 1);
    nacc0 += __shfl_xor(nacc0, 2);
    nacc1 += __shfl_xor(nacc1, 1);
    nacc1 += __shfl_xor(nacc1, 2);
    if (q == 0) {
        normpart[(mb0 * 16 + r) * 16 + seg]      = nacc0;
        normpart[(mb0 * 16 + 16 + r) * 16 + seg] = nacc1;
    }

    // C/D: col = lane&15, row = (lane>>4)*4 + rr
    constexpr int F = NBLK * 16;
#pragma unroll
    for (int m = 0; m < 2; ++m)
#pragma unroll
        for (int nb = 0; nb < NBLK; ++nb)
#pragma unroll
            for (int rr = 0; rr < 4; ++rr)
                outp[((size_t)seg * NN + mb0 * 16 + m * 16 + fg * 4 + rr) * F
                     + nb * 16 + fr] = acc[m][nb][rr];
}

// ---------------------------------------------------------------------------
// R1: h1[i][f] = sum_seg outp1 / (sqrt(sum_p normpart1[i][p]) + 1e-10)
// ---------------------------------------------------------------------------
__global__ __launch_bounds__(256) void r1_kernel(
    const float* __restrict__ outp, const float* __restrict__ normpart,
    float* __restrict__ h1)
{
    int tid = blockIdx.x * 256 + threadIdx.x;
    int i = tid >> 6, f = tid & 63;
    float s = 0.f;
#pragma unroll
    for (int sg = 0; sg < 16; ++sg)
        s += outp[((size_t)sg * NN + i) * 64 + f];
    float n = 0.f;
#pragma unroll
    for (int p = 0; p < 16; ++p) n += normpart[i * 16 + p];
    h1[tid] = s / (sqrtf(n) + 1e-10f);
}

// ---------------------------------------------------------------------------
// P2: z = h1 @ W2, written DIRECTLY as zB fragments (padded cols 10..15 = 0);
// fsrc2/edst2 = exp(-z . a2 halves). Replaces p2 + swizzle2.
// ---------------------------------------------------------------------------
__global__ __launch_bounds__(256) void p2_kernel(
    const float* __restrict__ h1, const float* __restrict__ W2,
    const float* __restrict__ a2, short* __restrict__ zB,
    float* __restrict__ fsrc2, float* __restrict__ edst2)
{
    int i = blockIdx.x * 256 + threadIdx.x;
    if (i >= NN) return;
    float zz[10];
#pragma unroll
    for (int c = 0; c < 10; ++c) zz[c] = 0.f;
    for (int f = 0; f < 64; ++f) {
        float hv = h1[(size_t)i * 64 + f];
#pragma unroll
        for (int c = 0; c < 10; ++c) zz[c] = fmaf(hv, W2[f * 10 + c], zz[c]);
    }
    float s1 = 0.f, s2 = 0.f;
    const int kb   = i >> 5;
    const int rowk = i & 31;
    const int lhi  = (rowk >> 3) << 4;
    const int j    = rowk & 7;
#pragma unroll
    for (int c = 0; c < 10; ++c) {
        s1 = fmaf(zz[c], a2[c], s1);
        s2 = fmaf(zz[c], a2[10 + c], s2);
        zB[((size_t)kb * 64 + (lhi | c)) * 8 + j] = (short)f2bfu(zz[c]);
    }
#pragma unroll
    for (int c = 10; c < 16; ++c)
        zB[((size_t)kb * 64 + (lhi | c)) * 8 + j] = 0;
    fsrc2[i] = expneg(s1);
    edst2[i] = expneg(s2);
}

// ---------------------------------------------------------------------------
// R2: h2 = partials/norm, then log_softmax over 10 classes -> d_out
// ---------------------------------------------------------------------------
__global__ __launch_bounds__(256) void r2_kernel(
    const float* __restrict__ outp, const float* __restrict__ normpart,
    float* __restrict__ out)
{
    int i = blockIdx.x * 256 + threadIdx.x;
    if (i >= NN) return;
    float n = 0.f;
#pragma unroll
    for (int p = 0; p < 16; ++p) n += normpart[i * 16 + p];
    float inv = 1.0f / (sqrtf(n) + 1e-10f);
    float v[10];
    float m = -1e30f;
#pragma unroll
    for (int c = 0; c < 10; ++c) {
        float s = 0.f;
#pragma unroll
        for (int sg = 0; sg < 16; ++sg)
            s += outp[((size_t)sg * NN + i) * 16 + c];
        v[c] = s * inv;
        m = fmaxf(m, v[c]);
    }
    float es = 0.f;
#pragma unroll
    for (int c = 0; c < 10; ++c) es += expf(v[c] - m);
    float lse = m + logf(es);
#pragma unroll
    for (int c = 0; c < 10; ++c) out[(size_t)i * 10 + c] = v[c] - lse;
}

extern "C" void kernel_launch(void* const* d_in, const int* in_sizes, int n_in,
                              void* d_out, int out_size, void* d_ws, size_t ws_size,
                              hipStream_t stream)
{
    const float* x   = (const float*)d_in[0];
    const float* adj = (const float*)d_in[1];
    const float* W1  = (const float*)d_in[2];
    const float* a1  = (const float*)d_in[3];
    const float* W2  = (const float*)d_in[4];
    const float* a2  = (const float*)d_in[5];
    float* out = (float*)d_out;

    char* ws = (char*)d_ws;
    size_t off = 0;
    auto alloc = [&](size_t bytes) -> void* {
        void* p = ws + off;
        off += (bytes + 255) & ~(size_t)255;
        return p;
    };
    float* h      = (float*)alloc((size_t)NN * 64 * 4);
    float* fsrc1  = (float*)alloc((size_t)NN * 4);
    float* edst1  = (float*)alloc((size_t)NN * 4);
    short* hB1    = (short*)alloc((size_t)NN * 64 * 2);
    float* outp1  = (float*)alloc((size_t)16 * NN * 64 * 4);     // 33.5MB
    float* normp1 = (float*)alloc((size_t)NN * 16 * 4);
    float* h1     = (float*)alloc((size_t)NN * 64 * 4);
    float* fsrc2  = (float*)alloc((size_t)NN * 4);
    float* edst2  = (float*)alloc((size_t)NN * 4);
    short* zB     = (short*)alloc((size_t)NN * 16 * 2);
    float* outp2  = (float*)alloc((size_t)16 * NN * 16 * 4);     // 8.4MB
    float* normp2 = (float*)alloc((size_t)NN * 16 * 4);

    hipLaunchKernelGGL(p1_kernel, dim3(NN / 8), dim3(256), 0, stream,
                       x, W1, a1, h, fsrc1, edst1);
    hipLaunchKernelGGL(swizzle_kernel, dim3(2048), dim3(256), 0, stream,
                       h, hB1, 4, 64, NN * 64);
    hipLaunchKernelGGL((fused_kernel<4>), dim3(32, 16), dim3(512), 0, stream,
                       adj, fsrc1, edst1, hB1, outp1, normp1);
    hipLaunchKernelGGL(r1_kernel, dim3(2048), dim3(256), 0, stream,
                       outp1, normp1, h1);
    hipLaunchKernelGGL(p2_kernel, dim3(32), dim3(256), 0, stream,
                       h1, W2, a2, zB, fsrc2, edst2);
    hipLaunchKernelGGL((fused_kernel<1>), dim3(32, 16), dim3(512), 0, stream,
                       adj, fsrc2, edst2, zB, outp2, normp2);
    hipLaunchKernelGGL(r2_kernel, dim3(32), dim3(256), 0, stream,
                       outp2, normp2, out);
}